// Round 17
// baseline (66.658 us; speedup 1.0000x reference)
//
#include <hip/hip_runtime.h>

#define HIDN 1024
#define G3 3072
#define NVOCAB 32000

typedef __bf16 bf16x8 __attribute__((ext_vector_type(8)));
typedef float f32x4 __attribute__((ext_vector_type(4)));
typedef unsigned short ushort4v __attribute__((ext_vector_type(4)));

__device__ __forceinline__ unsigned short f2bf(float f) {
  union { float f; unsigned int u; } v; v.f = f;
  unsigned int u = v.u;
  return (unsigned short)((u + 0x7fffu + ((u >> 16) & 1u)) >> 16);
}

__device__ __forceinline__ float sigmoidf_(float x) {
  return 1.0f / (1.0f + __expf(-x));
}

// async global->LDS: 16B/lane, LDS dest = wave-uniform base + lane*16
__device__ __forceinline__ void gload16(const void* g, void* l) {
  __builtin_amdgcn_global_load_lds(
      (const __attribute__((address_space(1))) unsigned int*)g,
      (__attribute__((address_space(3))) unsigned int*)l, 16, 0, 0);
}

// ---------------------------------------------------------------------------
// 32-col GEMM core (round-8/13, unchanged): depth-2 counted-vmcnt pipeline,
// triple-buffered, pure global_load_lds staging. See round-13 comments.
// ---------------------------------------------------------------------------
template <bool AF32, bool GATHER>
__device__ __forceinline__ void gemm32(
    const void* __restrict__ Aptr, int lda, const int* __restrict__ rix,
    int k0, int Kh, const float* __restrict__ W, int ldw, int n0,
    const float* __restrict__ bias, float* __restrict__ C, int ldc,
    char* smem) {
  constexpr int ABYTES = AF32 ? 16384 : 8192;
  constexpr int SBUF = 4096 + ABYTES;
  constexpr int NA = AF32 ? 4 : 2;
  const int t = threadIdx.x;
  const int w = t >> 6, lane = t & 63;
  const int l15 = lane & 15, kg = lane >> 4;
  const int rh = w >> 1, ct = w & 1;

  f32x4 acc[4];
#pragma unroll
  for (int r = 0; r < 4; ++r) acc[r] = (f32x4)0.0f;

  const size_t srcB = (size_t)(w * 8 + (lane >> 3)) * ldw + n0 +
                      ((lane & 7) ^ ((w & 1) << 2)) * 4;
  size_t srcA[NA];
  if constexpr (AF32) {
#pragma unroll
    for (int m = 0; m < NA; ++m) {
      int row = (w * 4 + m) * 8 + (lane >> 3);
      size_t rb;
      if constexpr (GATHER)
        rb = (size_t)rix[row] * lda;
      else
        rb = (size_t)row * lda;
      srcA[m] = rb + (((lane & 7) ^ (row & 7)) << 2);
    }
  } else {
#pragma unroll
    for (int m = 0; m < NA; ++m) {
      int g = (w * 2 + m) * 64 + lane;
      int row = g >> 2, uq = g & 3;
      srcA[m] = (size_t)row * lda + ((uq ^ ((row >> 1) & 3)) << 3);
    }
  }

  auto stage = [&](int c, int sel) {
    char* bb = smem + sel * SBUF;
    char* ab = bb + 4096;
    const int kbase = k0 + c * 32;
    gload16(W + (size_t)kbase * ldw + srcB, bb + w * 1024);
    if constexpr (AF32) {
#pragma unroll
      for (int m = 0; m < NA; ++m)
        gload16((const float*)Aptr + srcA[m] + kbase, ab + (w * 4 + m) * 1024);
    } else {
#pragma unroll
      for (int m = 0; m < NA; ++m)
        gload16((const unsigned short*)Aptr + srcA[m] + kbase,
                ab + (w * 2 + m) * 1024);
    }
  };

  const int NC = Kh >> 5;
  stage(0, 0);
  stage(1, 1);

  const int cl = ct * 16 + l15;
  for (int c = 0; c < NC; ++c) {
    if (c + 1 < NC) {
      if constexpr (AF32)
        asm volatile("s_waitcnt vmcnt(5)" ::: "memory");
      else
        asm volatile("s_waitcnt vmcnt(3)" ::: "memory");
    } else {
      asm volatile("s_waitcnt vmcnt(0)" ::: "memory");
    }
    __builtin_amdgcn_s_barrier();
    asm volatile("" ::: "memory");

    if (c + 2 < NC) stage(c + 2, (c + 2) % 3);

    const int sel = c % 3;
    const float* bbf = (const float*)(smem + sel * SBUF);
    const char* abf = smem + sel * SBUF + 4096;

    bf16x8 bfr;
#pragma unroll
    for (int j = 0; j < 8; ++j) {
      int r = kg * 8 + j;
      int q = (cl >> 2) ^ (((r >> 3) & 1) << 2);
      bfr[j] = (__bf16)bbf[r * 32 + q * 4 + (cl & 3)];
    }
#pragma unroll
    for (int rt = 0; rt < 4; ++rt) {
      const int row = rh * 64 + rt * 16 + l15;
      bf16x8 af;
      if constexpr (AF32) {
        const float* ar = (const float*)abf + row * 32;
        float4 fa = *(const float4*)(ar + (((kg * 2 + 0) ^ (l15 & 7)) << 2));
        float4 fb = *(const float4*)(ar + (((kg * 2 + 1) ^ (l15 & 7)) << 2));
        af[0] = (__bf16)fa.x; af[1] = (__bf16)fa.y;
        af[2] = (__bf16)fa.z; af[3] = (__bf16)fa.w;
        af[4] = (__bf16)fb.x; af[5] = (__bf16)fb.y;
        af[6] = (__bf16)fb.z; af[7] = (__bf16)fb.w;
      } else {
        af = *(const bf16x8*)((const unsigned short*)abf + row * 32 +
                              ((kg ^ ((row >> 1) & 3)) << 3));
      }
      acc[rt] =
          __builtin_amdgcn_mfma_f32_16x16x32_bf16(af, bfr, acc[rt], 0, 0, 0);
    }
  }

  const int col = n0 + cl;
  const float bs = bias ? bias[col] : 0.0f;
#pragma unroll
  for (int rt = 0; rt < 4; ++rt) {
    const int rb = rh * 64 + rt * 16 + kg * 4;
#pragma unroll
    for (int j = 0; j < 4; ++j)
      C[(size_t)(rb + j) * ldc + col] = acc[rt][j] + bs;
  }
}

// ---------------------------------------------------------------------------
// GRU gemms (unchanged round-13): 384 blocks = {mat} x {ksplit} x {96 cb}.
// ---------------------------------------------------------------------------
template <bool XF32>
__global__ __launch_bounds__(256) void gru_gemms_kernel(
    const void* __restrict__ X, int KX, const int* __restrict__ xidx,
    const float* __restrict__ H, const float* __restrict__ Wi,
    const float* __restrict__ bi, const float* __restrict__ Wr,
    const float* __restrict__ br, float* __restrict__ giP,
    float* __restrict__ grP) {
  __shared__ char smem[3 * 20480];
  const int bid = blockIdx.x;
  const int mat = bid / 192, rem = bid % 192;
  const int ks = rem / 96, cb = rem % 96;
  if (mat == 0) {
    const int Kh = KX >> 1;
    gemm32<XF32, XF32>(X, KX, xidx, ks * Kh, Kh, Wi, G3, cb * 32,
                       ks ? nullptr : bi, giP + (size_t)ks * 128 * G3, G3,
                       smem);
  } else {
    gemm32<true, false>(H, HIDN, nullptr, ks * 512, 512, Wr, G3, cb * 32,
                        ks ? nullptr : br, grP + (size_t)ks * 128 * G3, G3,
                        smem);
  }
}

// ---------------------------------------------------------------------------
// gates (unchanged round-13)
// ---------------------------------------------------------------------------
__global__ __launch_bounds__(256) void gates_kernel(
    const float* __restrict__ giP, const float* __restrict__ grP,
    const float* __restrict__ hfp, float* __restrict__ hout,
    ushort4v* __restrict__ hbf) {
  int i4 = blockIdx.x * 256 + threadIdx.x;
  int b = i4 >> 8, n = (i4 & 255) * 4;
  const float* g0 = giP + (size_t)b * G3;
  const float* g1 = g0 + (size_t)128 * G3;
  const float* r0 = grP + (size_t)b * G3;
  const float* r1 = r0 + (size_t)128 * G3;
  float4 izv = *(const float4*)(g0 + n);
  float4 izw = *(const float4*)(g1 + n);
  float4 rzv = *(const float4*)(r0 + n);
  float4 rzw = *(const float4*)(r1 + n);
  float4 irv = *(const float4*)(g0 + 1024 + n);
  float4 irw = *(const float4*)(g1 + 1024 + n);
  float4 rrv = *(const float4*)(r0 + 1024 + n);
  float4 rrw = *(const float4*)(r1 + 1024 + n);
  float4 ihv = *(const float4*)(g0 + 2048 + n);
  float4 ihw = *(const float4*)(g1 + 2048 + n);
  float4 rhv = *(const float4*)(r0 + 2048 + n);
  float4 rhw = *(const float4*)(r1 + 2048 + n);
  float4 hv = *(const float4*)(hfp + (size_t)b * HIDN + n);
  float4 ov;
  ushort4v obf;
#pragma unroll
  for (int j = 0; j < 4; ++j) {
    float iz = (&izv.x)[j] + (&izw.x)[j], rz = (&rzv.x)[j] + (&rzw.x)[j];
    float ir = (&irv.x)[j] + (&irw.x)[j], rr = (&rrv.x)[j] + (&rrw.x)[j];
    float ih = (&ihv.x)[j] + (&ihw.x)[j], rh = (&rhv.x)[j] + (&rhw.x)[j];
    float z = sigmoidf_(iz + rz);
    float r = sigmoidf_(ir + rr);
    float hh = tanhf(ih + r * rh);
    float h = (&hv.x)[j];
    float o = z * h + (1.0f - z) * hh;
    (&ov.x)[j] = o;
    obf[j] = f2bf(o);
  }
  *(float4*)(hout + (size_t)b * HIDN + n) = ov;
  hbf[i4] = obf;
}

// ---------------------------------------------------------------------------
// FF GEMM — round-16 B^T-in-LDS design with the register-rotation FIX:
// bv0 holds EVEN chunks, bv1 ODD. At iter c the free set (chunk c, already
// in LDS) is (c&1)? bv1 : bv0 -> receives chunk c+2; end-of-iter writeB
// writes chunk c+1 from (c&1)? bv0 : bv1.  [round-16 bug: both inverted]
// B-fragment = ONE ds_read_b128 (was 8 ds_read_b32). A stays pure gload16.
// LDS = 3 x (8KB A + 4KB B^T) = 36KB -> 4 blocks/CU.
// Ledger: writeB's implicit reg-wait brings outstanding <=12; explicit
// vmcnt(10) at iter top retires stageA(c)'s 2 gloads; lgkmcnt(0) drains
// ds_writes; barrier. Last iter vmcnt(0).
// ---------------------------------------------------------------------------
__global__ __launch_bounds__(256) void ff_kernel(
    const unsigned short* __restrict__ A, const float* __restrict__ W,
    const float* __restrict__ bias, float* __restrict__ C) {
  constexpr int SBUF = 12288;  // 8KB A + 4KB B^T
  __shared__ char smem[3 * SBUF];
  const int n0 = blockIdx.x * 64;
  const int t = threadIdx.x;
  const int w = t >> 6, lane = t & 63;
  const int l15 = lane & 15, kg = lane >> 4;

  f32x4 acc[8];
#pragma unroll
  for (int r = 0; r < 8; ++r) acc[r] = (f32x4)0.0f;

  // A staging (unchanged round-13)
  size_t srcA[2];
#pragma unroll
  for (int m = 0; m < 2; ++m) {
    int g = (w * 2 + m) * 64 + lane;
    int row = g >> 2, uq = g & 3;
    srcA[m] = (size_t)row * HIDN + ((uq ^ ((row >> 1) & 3)) << 3);
  }
  auto stageA = [&](int c, int sel) {
    char* ab = smem + sel * SBUF;
#pragma unroll
    for (int m = 0; m < 2; ++m)
      gload16(A + srcA[m] + c * 32, ab + (w * 2 + m) * 1024);
  };

  // B reg path: thread t owns (col = t&63, k-octet = t>>6)
  const int bc = t & 63, bu = t >> 6;
  const float* Wbase = W + (size_t)bu * 8 * NVOCAB + n0 + bc;
  const int bwoff = bc * 32 + ((bu ^ ((bc >> 1) & 3)) << 3);  // ushorts
  const int cl = w * 16 + l15;
  const int brdoff = cl * 32 + ((kg ^ ((cl >> 1) & 3)) << 3);  // ushorts

  float bv0[8], bv1[8];
  auto loadB = [&](int c, float* r8) {
    const float* p = Wbase + (size_t)c * 32 * NVOCAB;
#pragma unroll
    for (int j = 0; j < 8; ++j) r8[j] = p[(size_t)j * NVOCAB];
  };
  auto writeB = [&](const float* r8, int sel) {
    bf16x8 v;
#pragma unroll
    for (int j = 0; j < 8; ++j) v[j] = (__bf16)r8[j];
    *(bf16x8*)((unsigned short*)(smem + sel * SBUF + 8192) + bwoff) = v;
  };

  const int NC = HIDN >> 5;  // 32
  loadB(0, bv0);
  stageA(0, 0);
  loadB(1, bv1);
  stageA(1, 1);
  __builtin_amdgcn_sched_barrier(0);
  writeB(bv0, 0);  // compiler waits bv0 regs

  for (int c = 0; c < NC; ++c) {
    if (c + 1 < NC)
      asm volatile("s_waitcnt vmcnt(10) lgkmcnt(0)" ::: "memory");
    else
      asm volatile("s_waitcnt vmcnt(0) lgkmcnt(0)" ::: "memory");
    __builtin_amdgcn_s_barrier();
    asm volatile("" ::: "memory");

    // FIX: free reg set = the one holding chunk c (same parity as c)
    float* bnext = (c & 1) ? bv1 : bv0;
    if (c + 2 < NC) {
      loadB(c + 2, bnext);
      stageA(c + 2, (c + 2) % 3);
      __builtin_amdgcn_sched_barrier(0);
    }

    const int sel = c % 3;
    const unsigned short* abf = (const unsigned short*)(smem + sel * SBUF);
    const unsigned short* btf =
        (const unsigned short*)(smem + sel * SBUF + 8192);

    bf16x8 bfr = *(const bf16x8*)(btf + brdoff);
#pragma unroll
    for (int rt = 0; rt < 8; ++rt) {
      int row = rt * 16 + l15;
      bf16x8 af =
          *(const bf16x8*)(abf + row * 32 + ((kg ^ ((row >> 1) & 3)) << 3));
      acc[rt] =
          __builtin_amdgcn_mfma_f32_16x16x32_bf16(af, bfr, acc[rt], 0, 0, 0);
    }

    // FIX: chunk c+1 lives in the opposite-parity set
    if (c + 1 < NC) writeB((c & 1) ? bv0 : bv1, (c + 1) % 3);
  }

  const int col = n0 + cl;
  const float bs = bias[col];
#pragma unroll
  for (int rt = 0; rt < 8; ++rt) {
    int rb = rt * 16 + kg * 4;
#pragma unroll
    for (int j = 0; j < 4; ++j)
      C[(size_t)(rb + j) * NVOCAB + col] = acc[rt][j] + bs;
  }
}

extern "C" void kernel_launch(void* const* d_in, const int* in_sizes, int n_in,
                              void* d_out, int out_size, void* d_ws,
                              size_t ws_size, hipStream_t stream) {
  const int* x = (const int*)d_in[0];
  const float* h0 = (const float*)d_in[1];
  const float* h1 = (const float*)d_in[2];
  const float* emb = (const float*)d_in[3];
  const float* Wi0 = (const float*)d_in[4];
  const float* Wr0 = (const float*)d_in[5];
  const float* bi0 = (const float*)d_in[6];
  const float* br0 = (const float*)d_in[7];
  const float* Wi1 = (const float*)d_in[8];
  const float* Wr1 = (const float*)d_in[9];
  const float* bi1 = (const float*)d_in[10];
  const float* br1 = (const float*)d_in[11];
  const float* ffW = (const float*)d_in[12];
  const float* ffb = (const float*)d_in[13];

  float* out = (float*)d_out;
  float* logits = out;          // 128*32000
  float* h0n = out + 4096000;   // 128*1024
  float* h1n = out + 4227072;   // 128*1024

  float* giP = (float*)d_ws;                     // 2 * 128*3072
  float* grP = giP + 2 * 128 * G3;               // 2 * 128*3072
  unsigned short* h0nb = (unsigned short*)(grP + 2 * 128 * G3);  // 128*1024
  unsigned short* h1nb = h0nb + 131072;                          // 128*1024

  // GRU layer 0: X = emb rows gathered by x (fp32), H = h0 (fp32)
  gru_gemms_kernel<true><<<384, 256, 0, stream>>>(emb, 256, x, h0, Wi0, bi0,
                                                  Wr0, br0, giP, grP);
  gates_kernel<<<128, 256, 0, stream>>>(giP, grP, h0, h0n, (ushort4v*)h0nb);

  // GRU layer 1: X = h0n (bf16), H = h1 (fp32)
  gru_gemms_kernel<false><<<384, 256, 0, stream>>>(h0nb, 1024, nullptr, h1,
                                                   Wi1, bi1, Wr1, br1, giP,
                                                   grP);
  gates_kernel<<<128, 256, 0, stream>>>(giP, grP, h1, h1n, (ushort4v*)h1nb);

  // FF
  ff_kernel<<<500, 256, 0, stream>>>(h1nb, ffW, ffb, logits);
}

// Round 18
// 56.176 us; speedup vs baseline: 1.1866x; 1.1866x over previous
//
#include <hip/hip_runtime.h>

#define HIDN 1024
#define G3 3072
#define NVOCAB 32000

typedef __bf16 bf16x8 __attribute__((ext_vector_type(8)));
typedef float f32x4 __attribute__((ext_vector_type(4)));
typedef unsigned short ushort4v __attribute__((ext_vector_type(4)));

__device__ __forceinline__ unsigned short f2bf(float f) {
  union { float f; unsigned int u; } v; v.f = f;
  unsigned int u = v.u;
  return (unsigned short)((u + 0x7fffu + ((u >> 16) & 1u)) >> 16);
}

__device__ __forceinline__ float sigmoidf_(float x) {
  return 1.0f / (1.0f + __expf(-x));
}

// async global->LDS: 16B/lane, LDS dest = wave-uniform base + lane*16
__device__ __forceinline__ void gload16(const void* g, void* l) {
  __builtin_amdgcn_global_load_lds(
      (const __attribute__((address_space(1))) unsigned int*)g,
      (__attribute__((address_space(3))) unsigned int*)l, 16, 0, 0);
}

// ---------------------------------------------------------------------------
// prep: h0,h1 -> bf16 ; embedding gather -> bf16 (float4-vectorized)
// ---------------------------------------------------------------------------
__global__ __launch_bounds__(256) void prep_kernel(
    const float* __restrict__ h0, const float* __restrict__ h1,
    const float* __restrict__ emb, const int* __restrict__ x,
    ushort4v* __restrict__ h0b, ushort4v* __restrict__ h1b,
    ushort4v* __restrict__ eb) {
  int i = blockIdx.x * 256 + threadIdx.x;  // 73728 total
  float4 v;
  ushort4v* dst;
  if (i < 32768) {
    v = ((const float4*)h0)[i];
    dst = h0b + i;
  } else if (i < 65536) {
    int j = i - 32768;
    v = ((const float4*)h1)[j];
    dst = h1b + j;
  } else {
    int j = i - 65536;  // 8192
    int b = j >> 6, c = j & 63;
    v = ((const float4*)(emb + (size_t)x[b] * 256))[c];
    dst = eb + j;
  }
  ushort4v o;
  o[0] = f2bf(v.x); o[1] = f2bf(v.y); o[2] = f2bf(v.z); o[3] = f2bf(v.w);
  *dst = o;
}

// ---------------------------------------------------------------------------
// 32-col GEMM core (round-8 winner): depth-2 counted-vmcnt pipeline,
// triple-buffered LDS (3 x 12 KB). Per chunk: s_waitcnt vmcnt(3) retires
// exactly stage(c)'s 3 loads/wave while stage(c+1)'s stay in flight across
// the barrier; stage(c+2) issued right after the barrier.
// B [32k][32col] fp32 unit-XOR swizzled (2-way max b32 frag reads);
// A [128row][32k] bf16 preswizzled -> conflict-free ds_read_b128.
// ---------------------------------------------------------------------------
__device__ __forceinline__ void gemm_rows32(
    const unsigned short* __restrict__ A, int lda, int k0, int Kh,
    const float* __restrict__ W, int ldw, int n0,
    const float* __restrict__ bias, float* __restrict__ C, int ldc,
    char* smem) {
  const int t = threadIdx.x;
  const int w = t >> 6, lane = t & 63;
  const int l15 = lane & 15, kg = lane >> 4;
  const int rh = w >> 1, ct = w & 1;

  f32x4 acc[4];
#pragma unroll
  for (int r = 0; r < 4; ++r) acc[r] = (f32x4)0.0f;

  const size_t srcB = (size_t)(w * 8 + (lane >> 3)) * ldw + n0 +
                      ((lane & 7) ^ ((w & 1) << 2)) * 4;
  size_t srcA[2];
#pragma unroll
  for (int m = 0; m < 2; ++m) {
    int g = (w * 2 + m) * 64 + lane;
    int row = g >> 2, uq = g & 3;
    int up = uq ^ ((row >> 1) & 3);
    srcA[m] = (size_t)row * lda + up * 8;
  }

  auto stage = [&](int c, int sel) {
    char* bb = smem + sel * 12288;  // 4KB B + 8KB A per buffer
    char* ab = bb + 4096;
    int kbase = k0 + c * 32;
    gload16(W + (size_t)kbase * ldw + srcB, bb + w * 1024);
#pragma unroll
    for (int m = 0; m < 2; ++m)
      gload16(A + srcA[m] + kbase, ab + (w * 2 + m) * 1024);
  };

  const int NC = Kh >> 5;
  stage(0, 0);
  stage(1, 1);

  const int cl = ct * 16 + l15;
  for (int c = 0; c < NC; ++c) {
    if (c + 1 < NC)
      asm volatile("s_waitcnt vmcnt(3)" ::: "memory");
    else
      asm volatile("s_waitcnt vmcnt(0)" ::: "memory");
    __builtin_amdgcn_s_barrier();
    asm volatile("" ::: "memory");

    if (c + 2 < NC) stage(c + 2, (c + 2) % 3);

    int sel = c % 3;
    const float* bbf = (const float*)(smem + sel * 12288);
    const unsigned short* abf =
        (const unsigned short*)(smem + sel * 12288 + 4096);

    bf16x8 bfr;
#pragma unroll
    for (int j = 0; j < 8; ++j) {
      int r = kg * 8 + j;
      int q = (cl >> 2) ^ (((r >> 3) & 1) << 2);
      bfr[j] = (__bf16)bbf[r * 32 + q * 4 + (cl & 3)];
    }
#pragma unroll
    for (int rt = 0; rt < 4; ++rt) {
      int row = rh * 64 + rt * 16 + l15;
      bf16x8 af =
          *(const bf16x8*)(abf + row * 32 + ((kg ^ ((row >> 1) & 3)) << 3));
      acc[rt] =
          __builtin_amdgcn_mfma_f32_16x16x32_bf16(af, bfr, acc[rt], 0, 0, 0);
    }
  }

  const int col = n0 + cl;
  const float bs = bias ? bias[col] : 0.0f;
#pragma unroll
  for (int rt = 0; rt < 4; ++rt) {
    int rb = rh * 64 + rt * 16 + kg * 4;
#pragma unroll
    for (int j = 0; j < 4; ++j)
      C[(size_t)(rb + j) * ldc + col] = acc[rt][j] + bs;
  }
}

// ---------------------------------------------------------------------------
// GRU gemms: 384 blocks = {mat gi|gr} x {ksplit 0|1} x {96 col-blocks of 32}.
// ---------------------------------------------------------------------------
__global__ __launch_bounds__(256) void gru_gemms_kernel(
    const unsigned short* __restrict__ Xbf, int KX,
    const float* __restrict__ Wi, const float* __restrict__ bi,
    const unsigned short* __restrict__ Hbf,
    const float* __restrict__ Wr, const float* __restrict__ br,
    float* __restrict__ giP, float* __restrict__ grP) {
  __shared__ char smem[36864];  // 3 x 12 KB
  int bid = blockIdx.x;
  int mat = bid / 192, rem = bid % 192;
  int ks = rem / 96, cb = rem % 96;
  if (mat == 0) {
    int Kh = KX >> 1;
    gemm_rows32(Xbf, KX, ks * Kh, Kh, Wi, G3, cb * 32, ks ? nullptr : bi,
                giP + (size_t)ks * 128 * G3, G3, smem);
  } else {
    gemm_rows32(Hbf, HIDN, ks * 512, 512, Wr, G3, cb * 32, ks ? nullptr : br,
                grP + (size_t)ks * 128 * G3, G3, smem);
  }
}

// ---------------------------------------------------------------------------
// gates: sums K-partials, GRU elementwise; float4-vectorized
// ---------------------------------------------------------------------------
__global__ __launch_bounds__(256) void gates_kernel(
    const float* __restrict__ giP, const float* __restrict__ grP,
    const float* __restrict__ hfp, float* __restrict__ hout,
    ushort4v* __restrict__ hbf) {
  int i4 = blockIdx.x * 256 + threadIdx.x;  // 32768 total
  int b = i4 >> 8, n = (i4 & 255) * 4;
  const float* g0 = giP + (size_t)b * G3;
  const float* g1 = g0 + (size_t)128 * G3;
  const float* r0 = grP + (size_t)b * G3;
  const float* r1 = r0 + (size_t)128 * G3;
  float4 izv = *(const float4*)(g0 + n);
  float4 izw = *(const float4*)(g1 + n);
  float4 rzv = *(const float4*)(r0 + n);
  float4 rzw = *(const float4*)(r1 + n);
  float4 irv = *(const float4*)(g0 + 1024 + n);
  float4 irw = *(const float4*)(g1 + 1024 + n);
  float4 rrv = *(const float4*)(r0 + 1024 + n);
  float4 rrw = *(const float4*)(r1 + 1024 + n);
  float4 ihv = *(const float4*)(g0 + 2048 + n);
  float4 ihw = *(const float4*)(g1 + 2048 + n);
  float4 rhv = *(const float4*)(r0 + 2048 + n);
  float4 rhw = *(const float4*)(r1 + 2048 + n);
  float4 hv = *(const float4*)(hfp + (size_t)b * HIDN + n);
  float4 ov;
  ushort4v obf;
#pragma unroll
  for (int j = 0; j < 4; ++j) {
    float iz = (&izv.x)[j] + (&izw.x)[j], rz = (&rzv.x)[j] + (&rzw.x)[j];
    float ir = (&irv.x)[j] + (&irw.x)[j], rr = (&rrv.x)[j] + (&rrw.x)[j];
    float ih = (&ihv.x)[j] + (&ihw.x)[j], rh = (&rhv.x)[j] + (&rhw.x)[j];
    float z = sigmoidf_(iz + rz);
    float r = sigmoidf_(ir + rr);
    float hh = tanhf(ih + r * rh);
    float h = (&hv.x)[j];
    float o = z * h + (1.0f - z) * hh;
    (&ov.x)[j] = o;
    obf[j] = f2bf(o);
  }
  *(float4*)(hout + (size_t)b * HIDN + n) = ov;
  hbf[i4] = obf;
}

// ---------------------------------------------------------------------------
// FF GEMM (round-8 winner): 500 blocks x 256 thr; wave w owns all 128 rows
// x 16 cols; depth-2 counted-vmcnt pipeline, triple-buffered LDS (48 KB).
// ---------------------------------------------------------------------------
__global__ __launch_bounds__(256) void ff_kernel(
    const unsigned short* __restrict__ A, const float* __restrict__ W,
    const float* __restrict__ bias, float* __restrict__ C) {
  __shared__ char smem[49152];  // 3 x (8KB B + 8KB A)
  const int n0 = blockIdx.x * 64;
  const int t = threadIdx.x;
  const int w = t >> 6, lane = t & 63;
  const int l15 = lane & 15, kg = lane >> 4;

  f32x4 acc[8];
#pragma unroll
  for (int r = 0; r < 8; ++r) acc[r] = (f32x4)0.0f;

  size_t srcB[2], srcA[2];
#pragma unroll
  for (int m = 0; m < 2; ++m) {
    int g = (w * 2 + m) * 64 + lane;
    {
      int r = g >> 4, q = g & 15;
      int p = q ^ (((r >> 3) & 1) << 2);
      srcB[m] = (size_t)r * NVOCAB + n0 + p * 4;
    }
    {
      int row = g >> 2, uq = g & 3;
      int up = uq ^ ((row >> 1) & 3);
      srcA[m] = (size_t)row * HIDN + up * 8;
    }
  }

  auto stage = [&](int c, int sel) {
    char* bb = smem + sel * 8192;
    char* ab = smem + 24576 + sel * 8192;
    int kbase = c * 32;
#pragma unroll
    for (int m = 0; m < 2; ++m)
      gload16(W + (size_t)kbase * NVOCAB + srcB[m], bb + (w * 2 + m) * 1024);
#pragma unroll
    for (int m = 0; m < 2; ++m)
      gload16(A + srcA[m] + kbase, ab + (w * 2 + m) * 1024);
  };

  stage(0, 0);
  stage(1, 1);

  const int NC = HIDN >> 5;  // 32
  const int cl = w * 16 + l15;
  for (int c = 0; c < NC; ++c) {
    if (c + 1 < NC)
      asm volatile("s_waitcnt vmcnt(4)" ::: "memory");
    else
      asm volatile("s_waitcnt vmcnt(0)" ::: "memory");
    __builtin_amdgcn_s_barrier();
    asm volatile("" ::: "memory");

    if (c + 2 < NC) stage(c + 2, (c + 2) % 3);

    int sel = c % 3;
    const float* bbf = (const float*)(smem + sel * 8192);
    const unsigned short* abf =
        (const unsigned short*)(smem + 24576 + sel * 8192);

    bf16x8 bfr;
#pragma unroll
    for (int j = 0; j < 8; ++j) {
      int r = kg * 8 + j;
      int q = (cl >> 2) ^ (((r >> 3) & 1) << 2);
      bfr[j] = (__bf16)bbf[r * 64 + q * 4 + (cl & 3)];
    }
#pragma unroll
    for (int rt = 0; rt < 8; ++rt) {
      int row = rt * 16 + l15;
      bf16x8 af =
          *(const bf16x8*)(abf + row * 32 + ((kg ^ ((row >> 1) & 3)) << 3));
      acc[rt] =
          __builtin_amdgcn_mfma_f32_16x16x32_bf16(af, bfr, acc[rt], 0, 0, 0);
    }
  }

  const int col = n0 + cl;
  const float bs = bias[col];
#pragma unroll
  for (int rt = 0; rt < 8; ++rt) {
    int rb = rt * 16 + kg * 4;
#pragma unroll
    for (int j = 0; j < 4; ++j)
      C[(size_t)(rb + j) * NVOCAB + col] = acc[rt][j] + bs;
  }
}

extern "C" void kernel_launch(void* const* d_in, const int* in_sizes, int n_in,
                              void* d_out, int out_size, void* d_ws,
                              size_t ws_size, hipStream_t stream) {
  const int* x = (const int*)d_in[0];
  const float* h0 = (const float*)d_in[1];
  const float* h1 = (const float*)d_in[2];
  const float* emb = (const float*)d_in[3];
  const float* Wi0 = (const float*)d_in[4];
  const float* Wr0 = (const float*)d_in[5];
  const float* bi0 = (const float*)d_in[6];
  const float* br0 = (const float*)d_in[7];
  const float* Wi1 = (const float*)d_in[8];
  const float* Wr1 = (const float*)d_in[9];
  const float* bi1 = (const float*)d_in[10];
  const float* br1 = (const float*)d_in[11];
  const float* ffW = (const float*)d_in[12];
  const float* ffb = (const float*)d_in[13];

  float* out = (float*)d_out;
  float* logits = out;          // 128*32000
  float* h0n = out + 4096000;   // 128*1024
  float* h1n = out + 4227072;   // 128*1024

  unsigned short* h0b = (unsigned short*)d_ws;  // 128*1024
  unsigned short* h1b = h0b + 131072;           // 128*1024
  unsigned short* eb = h1b + 131072;            // 128*256
  unsigned short* h0nb = eb + 32768;            // 128*1024
  unsigned short* h1nb = h0nb + 131072;         // 128*1024
  float* giP = (float*)(h1nb + 131072);         // 2 * 128*3072
  float* grP = giP + 2 * 128 * G3;              // 2 * 128*3072

  prep_kernel<<<288, 256, 0, stream>>>(h0, h1, emb, x, (ushort4v*)h0b,
                                       (ushort4v*)h1b, (ushort4v*)eb);

  // GRU layer 0: x-part uses embedded input (K=256)
  gru_gemms_kernel<<<384, 256, 0, stream>>>(eb, 256, Wi0, bi0, h0b, Wr0, br0,
                                            giP, grP);
  gates_kernel<<<128, 256, 0, stream>>>(giP, grP, h0, h0n, (ushort4v*)h0nb);

  // GRU layer 1: x-part uses h0n (K=1024)
  gru_gemms_kernel<<<384, 256, 0, stream>>>(h0nb, 1024, Wi1, bi1, h1b, Wr1,
                                            br1, giP, grP);
  gates_kernel<<<128, 256, 0, stream>>>(giP, grP, h1, h1n, (ushort4v*)h1nb);

  // FF
  ff_kernel<<<500, 256, 0, stream>>>(h1nb, ffW, ffb, logits);
}